// Round 1
// baseline (303.558 us; speedup 1.0000x reference)
//
#include <hip/hip_runtime.h>
#include <math.h>

#define NG    1024      // graphs
#define NPG   64        // nodes per graph
#define EPG   512       // edges per graph
#define NNODE 65536
#define NEDGE 524288
#define HIDN  128
#define DINF  64
#define LDH   132       // padded LDS row stride (floats), 16B-aligned, breaks bank alias
#define LDF   65        // padded row stride for 64-wide fc output

__device__ __forceinline__ float gelu_exact(float v) {
    return 0.5f * v * (1.0f + erff(v * 0.70710678118654752440f));
}
__device__ __forceinline__ float fast_sigmoid(float v) {
    float e = __builtin_amdgcn_exp2f(v * -1.4426950408889634f);
    return __builtin_amdgcn_rcpf(1.0f + e);
}
__device__ __forceinline__ float fast_tanh(float v) {
    float e = __builtin_amdgcn_exp2f(v * 2.8853900817779268f);
    return 1.0f - 2.0f * __builtin_amdgcn_rcpf(1.0f + e);
}

// One GCN layer entirely in LDS: A (input h, [64][LDH]) -> Bf (hw) -> A (gelu(gcn)+...)
__device__ __forceinline__ void gcn_layer(
    float* A, float* Bf,
    const unsigned char* srl, const float* snorm,
    const float* dinv, const int* off,
    const float4* __restrict__ W4, const float* __restrict__ bb, int t)
{
    // ---- GEMM: hw[n][f] = sum_k A[n][k] * W[k][f]; thread: 8 nodes x 4 feats ----
    const int fq = t & 31;   // float4 column 0..31 (f = 4*fq)
    const int n0 = t >> 5;   // 0..7 ; nodes n0 + 8j
    float4 acc[8];
#pragma unroll
    for (int j = 0; j < 8; ++j) acc[j] = make_float4(0.f, 0.f, 0.f, 0.f);
#pragma unroll 2
    for (int k0 = 0; k0 < HIDN; k0 += 4) {
        float4 w0 = W4[(k0 + 0) * 32 + fq];
        float4 w1 = W4[(k0 + 1) * 32 + fq];
        float4 w2 = W4[(k0 + 2) * 32 + fq];
        float4 w3 = W4[(k0 + 3) * 32 + fq];
#pragma unroll
        for (int j = 0; j < 8; ++j) {
            float4 h4 = *(const float4*)&A[(n0 + 8 * j) * LDH + k0];
            acc[j].x = fmaf(h4.x, w0.x, acc[j].x);
            acc[j].y = fmaf(h4.x, w0.y, acc[j].y);
            acc[j].z = fmaf(h4.x, w0.z, acc[j].z);
            acc[j].w = fmaf(h4.x, w0.w, acc[j].w);
            acc[j].x = fmaf(h4.y, w1.x, acc[j].x);
            acc[j].y = fmaf(h4.y, w1.y, acc[j].y);
            acc[j].z = fmaf(h4.y, w1.z, acc[j].z);
            acc[j].w = fmaf(h4.y, w1.w, acc[j].w);
            acc[j].x = fmaf(h4.z, w2.x, acc[j].x);
            acc[j].y = fmaf(h4.z, w2.y, acc[j].y);
            acc[j].z = fmaf(h4.z, w2.z, acc[j].z);
            acc[j].w = fmaf(h4.z, w2.w, acc[j].w);
            acc[j].x = fmaf(h4.w, w3.x, acc[j].x);
            acc[j].y = fmaf(h4.w, w3.y, acc[j].y);
            acc[j].z = fmaf(h4.w, w3.z, acc[j].z);
            acc[j].w = fmaf(h4.w, w3.w, acc[j].w);
        }
    }
    // write hw -> Bf (A still only read elsewhere; different array, no sync needed)
#pragma unroll
    for (int j = 0; j < 8; ++j)
        *(float4*)&Bf[(n0 + 8 * j) * LDH + 4 * fq] = acc[j];
    __syncthreads();  // hw ready; also guarantees all A reads done

    // ---- scatter via CSR: each thread owns (node c, feature slice sl) ----
    const int c = t >> 2, sl = t & 3;
    const float selfw = dinv[c] * dinv[c];
    float4 o[8];
    {
        const float* brow = &Bf[c * LDH + sl * 32];
#pragma unroll
        for (int j = 0; j < 8; ++j) {
            float4 hv = *(const float4*)&brow[4 * j];
            o[j] = make_float4(selfw * hv.x, selfw * hv.y, selfw * hv.z, selfw * hv.w);
        }
    }
    const int e1 = off[c + 1];
    for (int e = off[c]; e < e1; ++e) {
        int r = srl[e];
        float wgt = snorm[e];
        const float* rrow = &Bf[r * LDH + sl * 32];
#pragma unroll
        for (int j = 0; j < 8; ++j) {
            float4 hv = *(const float4*)&rrow[4 * j];
            o[j].x = fmaf(wgt, hv.x, o[j].x);
            o[j].y = fmaf(wgt, hv.y, o[j].y);
            o[j].z = fmaf(wgt, hv.z, o[j].z);
            o[j].w = fmaf(wgt, hv.w, o[j].w);
        }
    }
    // bias + exact gelu -> A (safe: A no longer read this layer)
#pragma unroll
    for (int j = 0; j < 8; ++j) {
        int f = sl * 32 + 4 * j;
        float4 bv = *(const float4*)&bb[f];
        float4 rv;
        rv.x = gelu_exact(o[j].x + bv.x);
        rv.y = gelu_exact(o[j].y + bv.y);
        rv.z = gelu_exact(o[j].z + bv.z);
        rv.w = gelu_exact(o[j].w + bv.w);
        *(float4*)&A[c * LDH + f] = rv;
    }
    __syncthreads();
}

__global__ __launch_bounds__(256, 2) void fused_graph(
    const float* __restrict__ x, const float* __restrict__ emb,
    const float* __restrict__ W1, const float* __restrict__ b1,
    const float* __restrict__ W2, const float* __restrict__ b2,
    const float* __restrict__ W3, const float* __restrict__ b3,
    const float* __restrict__ fcW, const float* __restrict__ fcb,
    const float* __restrict__ Wih, const float* __restrict__ bih,
    const int* __restrict__ ei, float4* __restrict__ gi4)
{
    __shared__ float A[NPG * LDH];
    __shared__ float Bf[NPG * LDH];
    __shared__ unsigned char rl[EPG], cl[EPG], srl[EPG];
    __shared__ float snorm[EPG];
    __shared__ float dinv[NPG];
    __shared__ int cnt[NPG];
    __shared__ int off[NPG + 1];
    __shared__ float wih_s[3 * DINF];

    const int g = blockIdx.x;
    const int t = threadIdx.x;

    if (t < NPG) cnt[t] = 0;
    __syncthreads();

    // ---- load edges (local indices), in-degree count ----
    {
        const int gb = g * NPG;
        int i0 = t, i1 = t + 256;
        int r0 = ei[g * EPG + i0] - gb, c0 = ei[NEDGE + g * EPG + i0] - gb;
        int r1 = ei[g * EPG + i1] - gb, c1 = ei[NEDGE + g * EPG + i1] - gb;
        rl[i0] = (unsigned char)r0; cl[i0] = (unsigned char)c0;
        rl[i1] = (unsigned char)r1; cl[i1] = (unsigned char)c1;
        atomicAdd(&cnt[c0], 1);
        atomicAdd(&cnt[c1], 1);
    }
    __syncthreads();

    if (t < NPG) dinv[t] = rsqrtf((float)(cnt[t] + 1));  // +1 self loop
    if (t == 0) {
        int s = 0;
        for (int i = 0; i < NPG; ++i) { off[i] = s; s += cnt[i]; }
        off[NPG] = s;
    }
    __syncthreads();

    // ---- t<64: stable counting sort by dst  |  t>=64: stage h0 = [feat | emb[nid]] ----
    if (t < NPG) {
        int p = off[t];
        float dc = dinv[t];
#pragma unroll 4
        for (int i = 0; i < EPG; ++i) {
            if ((int)cl[i] == t) {
                int r = rl[i];
                srl[p] = (unsigned char)r;
                snorm[p] = dinv[r] * dc;
                ++p;
            }
        }
    } else {
        for (int idx = t - NPG; idx < NPG * HIDN; idx += 192) {
            int n = idx >> 7, k = idx & 127;
            const float* xr = x + (g * NPG + n) * 65;
            float v;
            if (k < DINF) v = xr[k];
            else v = emb[((int)xr[64]) * DINF + (k - DINF)];
            A[n * LDH + k] = v;
        }
        int widx = t - NPG;
        if (widx < 3 * DINF) wih_s[widx] = Wih[widx];
    }
    __syncthreads();

    gcn_layer(A, Bf, srl, snorm, dinv, off, (const float4*)W1, b1, t);
    gcn_layer(A, Bf, srl, snorm, dinv, off, (const float4*)W2, b2, t);
    gcn_layer(A, Bf, srl, snorm, dinv, off, (const float4*)W3, b3, t);

    // ---- fc: hfc = gelu(h3 @ fcW + fcb) -> Bf as [64][LDF] ----
    {
        const float4* FW4 = (const float4*)fcW;
        const int fq = t & 15;   // f = 4*fq, 0..63
        const int n0 = t >> 4;   // 0..15 ; nodes n0 + 16j
        float4 fa[4];
#pragma unroll
        for (int j = 0; j < 4; ++j) fa[j] = make_float4(0.f, 0.f, 0.f, 0.f);
#pragma unroll 2
        for (int k0 = 0; k0 < HIDN; k0 += 4) {
            float4 w0 = FW4[(k0 + 0) * 16 + fq];
            float4 w1 = FW4[(k0 + 1) * 16 + fq];
            float4 w2 = FW4[(k0 + 2) * 16 + fq];
            float4 w3 = FW4[(k0 + 3) * 16 + fq];
#pragma unroll
            for (int j = 0; j < 4; ++j) {
                float4 h4 = *(const float4*)&A[(n0 + 16 * j) * LDH + k0];
                fa[j].x = fmaf(h4.x, w0.x, fa[j].x);
                fa[j].y = fmaf(h4.x, w0.y, fa[j].y);
                fa[j].z = fmaf(h4.x, w0.z, fa[j].z);
                fa[j].w = fmaf(h4.x, w0.w, fa[j].w);
                fa[j].x = fmaf(h4.y, w1.x, fa[j].x);
                fa[j].y = fmaf(h4.y, w1.y, fa[j].y);
                fa[j].z = fmaf(h4.y, w1.z, fa[j].z);
                fa[j].w = fmaf(h4.y, w1.w, fa[j].w);
                fa[j].x = fmaf(h4.z, w2.x, fa[j].x);
                fa[j].y = fmaf(h4.z, w2.y, fa[j].y);
                fa[j].z = fmaf(h4.z, w2.z, fa[j].z);
                fa[j].w = fmaf(h4.z, w2.w, fa[j].w);
                fa[j].x = fmaf(h4.w, w3.x, fa[j].x);
                fa[j].y = fmaf(h4.w, w3.y, fa[j].y);
                fa[j].z = fmaf(h4.w, w3.z, fa[j].z);
                fa[j].w = fmaf(h4.w, w3.w, fa[j].w);
            }
        }
        float4 fb = *(const float4*)&fcb[4 * fq];
        // Bf's last readers finished at layer-3's ending barrier; safe to overwrite.
#pragma unroll
        for (int j = 0; j < 4; ++j) {
            int n = n0 + 16 * j;
            Bf[n * LDF + 4 * fq + 0] = gelu_exact(fa[j].x + fb.x);
            Bf[n * LDF + 4 * fq + 1] = gelu_exact(fa[j].y + fb.y);
            Bf[n * LDF + 4 * fq + 2] = gelu_exact(fa[j].z + fb.z);
            Bf[n * LDF + 4 * fq + 3] = gelu_exact(fa[j].w + fb.w);
        }
    }
    __syncthreads();

    // ---- per-edge GRU input: gi = (0.5*(h[r]+h[c])) @ Wih^T + bih ----
    {
        const float bi0 = bih[0], bi1 = bih[1], bi2 = bih[2];
#pragma unroll
        for (int rep = 0; rep < 2; ++rep) {
            int i = t + rep * 256;
            int r = rl[i], c = cl[i];
            const float* hr = &Bf[r * LDF];
            const float* hc = &Bf[c * LDF];
            float a0 = 0.f, a1 = 0.f, a2 = 0.f;
#pragma unroll 4
            for (int k = 0; k < DINF; ++k) {
                float xk = 0.5f * (hr[k] + hc[k]);
                a0 = fmaf(xk, wih_s[k], a0);
                a1 = fmaf(xk, wih_s[DINF + k], a1);
                a2 = fmaf(xk, wih_s[2 * DINF + k], a2);
            }
            gi4[g * EPG + i] = make_float4(a0 + bi0, a1 + bi1, a2 + bi2, 0.f);
        }
    }
}

__device__ __forceinline__ float gru_step(float h, float4 gi,
    float wr, float wz, float wn, float br, float bz, float bn)
{
    float r = fast_sigmoid(gi.x + fmaf(h, wr, br));
    float z = fast_sigmoid(gi.y + fmaf(h, wz, bz));
    float n = fast_tanh(fmaf(r, fmaf(h, wn, bn), gi.z));
    return fmaf(z, h - n, n);   // (1-z)*n + z*h
}

__global__ __launch_bounds__(64) void gru_scan(
    const float4* __restrict__ gi4,
    const float* __restrict__ Whh, const float* __restrict__ bhh,
    const float* __restrict__ init_hs, float* __restrict__ out)
{
    const int g = blockIdx.x * 64 + threadIdx.x;   // one thread per graph
    const float wr = Whh[0], wz = Whh[1], wn = Whh[2];
    const float br = bhh[0], bz = bhh[1], bn = bhh[2];
    float h = init_hs[0];
    float ssum = 0.f, lastval = 0.f, firstval = 0.f;
    int lastidx = -1;
    const float4* gp = gi4 + g * EPG;
    float* flat = out + NG + g * EPG;

    float4 g0 = gp[0], g1 = gp[1], g2 = gp[2], g3 = gp[3];
    for (int tt = 0; tt < EPG; tt += 4) {
        float4 p0, p1, p2, p3;
        if (tt + 4 < EPG) {  // software prefetch next 4 steps
            p0 = gp[tt + 4]; p1 = gp[tt + 5]; p2 = gp[tt + 6]; p3 = gp[tt + 7];
        } else { p0 = g0; p1 = g1; p2 = g2; p3 = g3; }
        float4 hq;
        h = gru_step(h, g0, wr, wz, wn, br, bz, bn); hq.x = h;
        h = gru_step(h, g1, wr, wz, wn, br, bz, bn); hq.y = h;
        h = gru_step(h, g2, wr, wz, wn, br, bz, bn); hq.z = h;
        h = gru_step(h, g3, wr, wz, wn, br, bz, bn); hq.w = h;
        *(float4*)&flat[tt] = hq;
        if (tt == 0) firstval = hq.x;
        ssum += ((hq.x + hq.y) + (hq.z + hq.w));
        if (hq.x != 0.f) { lastidx = tt;     lastval = hq.x; }
        if (hq.y != 0.f) { lastidx = tt + 1; lastval = hq.y; }
        if (hq.z != 0.f) { lastidx = tt + 2; lastval = hq.z; }
        if (hq.w != 0.f) { lastidx = tt + 3; lastval = hq.w; }
        g0 = p0; g1 = p1; g2 = p2; g3 = p3;
    }
    // last2 = (sum>0)? last1 : 0; last3 = max(last2,0); sel = pred[last3]
    float sel = (ssum > 0.f && lastidx >= 0) ? lastval : firstval;
    out[g] = sel;
}

extern "C" void kernel_launch(void* const* d_in, const int* in_sizes, int n_in,
                              void* d_out, int out_size, void* d_ws, size_t ws_size,
                              hipStream_t stream) {
    const float* x    = (const float*)d_in[0];
    const float* emb  = (const float*)d_in[1];
    const float* W1   = (const float*)d_in[2];
    const float* b1   = (const float*)d_in[3];
    const float* W2   = (const float*)d_in[4];
    const float* b2   = (const float*)d_in[5];
    const float* W3   = (const float*)d_in[6];
    const float* b3   = (const float*)d_in[7];
    const float* fcW  = (const float*)d_in[8];
    const float* fcb  = (const float*)d_in[9];
    const float* Wih  = (const float*)d_in[10];
    const float* Whh  = (const float*)d_in[11];
    const float* bih  = (const float*)d_in[12];
    const float* bhh  = (const float*)d_in[13];
    const float* ihs  = (const float*)d_in[14];
    const int*   ei   = (const int*)d_in[15];
    float* out = (float*)d_out;
    float4* gi4 = (float4*)d_ws;   // [NEDGE] float4 = 8 MB scratch

    fused_graph<<<dim3(NG), dim3(256), 0, stream>>>(
        x, emb, W1, b1, W2, b2, W3, b3, fcW, fcb, Wih, bih, ei, gi4);
    gru_scan<<<dim3(16), dim3(64), 0, stream>>>(gi4, Whh, bhh, ihs, out);
}

// Round 2
// 226.691 us; speedup vs baseline: 1.3391x; 1.3391x over previous
//
#include <hip/hip_runtime.h>
#include <math.h>

#define NG    1024      // graphs
#define NPG   64        // nodes per graph
#define EPG   512       // edges per graph
#define NNODE 65536
#define NEDGE 524288
#define HIDN  128
#define DINF  64
#define LDH   132       // padded LDS row stride (floats) for 128-wide h
#define LDF   65        // padded row stride for 64-wide fc output

__device__ __forceinline__ float gelu_exact(float v) {
    return 0.5f * v * (1.0f + erff(v * 0.70710678118654752440f));
}
__device__ __forceinline__ float fast_sigmoid(float v) {
    float e = __builtin_amdgcn_exp2f(v * -1.4426950408889634f);
    return __builtin_amdgcn_rcpf(1.0f + e);
}
__device__ __forceinline__ float fast_tanh(float v) {
    float e = __builtin_amdgcn_exp2f(v * 2.8853900817779268f);
    return 1.0f - 2.0f * __builtin_amdgcn_rcpf(1.0f + e);
}

// One GCN layer IN-PLACE in A[64][LDH]:
//   h -> (GEMM to regs) -> sync -> hw into A -> sync -> (scatter to regs)
//   -> sync -> gelu(hw_agg + b) into A -> sync
__device__ __forceinline__ void gcn_layer(
    float* A,
    const unsigned char* srl, const float* snorm,
    const float* dinv, const int* off,
    const float4* __restrict__ W4, const float* __restrict__ bb, int t)
{
    // ---- GEMM: hw[n][f] = sum_k A[n][k] * W[k][f]; thread: 8 nodes x 4 feats ----
    const int fq = t & 31;   // float4 column 0..31 (f = 4*fq)
    const int n0 = t >> 5;   // 0..7 ; nodes n0 + 8j
    float4 acc[8];
#pragma unroll
    for (int j = 0; j < 8; ++j) acc[j] = make_float4(0.f, 0.f, 0.f, 0.f);
#pragma unroll 2
    for (int k0 = 0; k0 < HIDN; k0 += 4) {
        float4 w0 = W4[(k0 + 0) * 32 + fq];
        float4 w1 = W4[(k0 + 1) * 32 + fq];
        float4 w2 = W4[(k0 + 2) * 32 + fq];
        float4 w3 = W4[(k0 + 3) * 32 + fq];
#pragma unroll
        for (int j = 0; j < 8; ++j) {
            float4 h4 = *(const float4*)&A[(n0 + 8 * j) * LDH + k0];
            acc[j].x = fmaf(h4.x, w0.x, acc[j].x);
            acc[j].y = fmaf(h4.x, w0.y, acc[j].y);
            acc[j].z = fmaf(h4.x, w0.z, acc[j].z);
            acc[j].w = fmaf(h4.x, w0.w, acc[j].w);
            acc[j].x = fmaf(h4.y, w1.x, acc[j].x);
            acc[j].y = fmaf(h4.y, w1.y, acc[j].y);
            acc[j].z = fmaf(h4.y, w1.z, acc[j].z);
            acc[j].w = fmaf(h4.y, w1.w, acc[j].w);
            acc[j].x = fmaf(h4.z, w2.x, acc[j].x);
            acc[j].y = fmaf(h4.z, w2.y, acc[j].y);
            acc[j].z = fmaf(h4.z, w2.z, acc[j].z);
            acc[j].w = fmaf(h4.z, w2.w, acc[j].w);
            acc[j].x = fmaf(h4.w, w3.x, acc[j].x);
            acc[j].y = fmaf(h4.w, w3.y, acc[j].y);
            acc[j].z = fmaf(h4.w, w3.z, acc[j].z);
            acc[j].w = fmaf(h4.w, w3.w, acc[j].w);
        }
    }
    __syncthreads();   // all reads of h done; safe to overwrite A
#pragma unroll
    for (int j = 0; j < 8; ++j)
        *(float4*)&A[(n0 + 8 * j) * LDH + 4 * fq] = acc[j];
    __syncthreads();   // hw ready

    // ---- scatter via CSR: each thread owns (node c, feature slice sl) ----
    const int c = t >> 2, sl = t & 3;
    const float selfw = dinv[c] * dinv[c];
    float4 o[8];
    {
        const float* brow = &A[c * LDH + sl * 32];
#pragma unroll
        for (int j = 0; j < 8; ++j) {
            float4 hv = *(const float4*)&brow[4 * j];
            o[j] = make_float4(selfw * hv.x, selfw * hv.y, selfw * hv.z, selfw * hv.w);
        }
    }
    const int e1 = off[c + 1];
    for (int e = off[c]; e < e1; ++e) {
        int r = srl[e];
        float wgt = snorm[e];
        const float* rrow = &A[r * LDH + sl * 32];
#pragma unroll
        for (int j = 0; j < 8; ++j) {
            float4 hv = *(const float4*)&rrow[4 * j];
            o[j].x = fmaf(wgt, hv.x, o[j].x);
            o[j].y = fmaf(wgt, hv.y, o[j].y);
            o[j].z = fmaf(wgt, hv.z, o[j].z);
            o[j].w = fmaf(wgt, hv.w, o[j].w);
        }
    }
    __syncthreads();   // all reads of hw done; safe to overwrite A
#pragma unroll
    for (int j = 0; j < 8; ++j) {
        int f = sl * 32 + 4 * j;
        float4 bv = *(const float4*)&bb[f];
        float4 rv;
        rv.x = gelu_exact(o[j].x + bv.x);
        rv.y = gelu_exact(o[j].y + bv.y);
        rv.z = gelu_exact(o[j].z + bv.z);
        rv.w = gelu_exact(o[j].w + bv.w);
        *(float4*)&A[c * LDH + f] = rv;
    }
    __syncthreads();
}

__global__ __launch_bounds__(256, 4) void fused_graph(
    const float* __restrict__ x, const float* __restrict__ emb,
    const float* __restrict__ W1, const float* __restrict__ b1,
    const float* __restrict__ W2, const float* __restrict__ b2,
    const float* __restrict__ W3, const float* __restrict__ b3,
    const float* __restrict__ fcW, const float* __restrict__ fcb,
    const float* __restrict__ Wih, const float* __restrict__ bih,
    const int* __restrict__ ei, float4* __restrict__ gi4)
{
    __shared__ float A[NPG * LDH];                 // 33 KB, reused every phase
    __shared__ unsigned char rl[EPG], cl[EPG], srl[EPG];
    __shared__ float snorm[EPG];
    __shared__ float dinv[NPG];
    __shared__ int cnt[NPG], cnt2[NPG];
    __shared__ int off[NPG + 1];
    __shared__ float wih_s[3 * DINF];

    const int g = blockIdx.x;
    const int t = threadIdx.x;

    if (t < NPG) { cnt[t] = 0; cnt2[t] = 0; }
    __syncthreads();

    // ---- load edges (2/thread), in-degree count; stage h0 in parallel ----
    const int gb = g * NPG;
    const int i0 = t, i1 = t + 256;
    const int r0 = ei[g * EPG + i0] - gb, c0 = ei[NEDGE + g * EPG + i0] - gb;
    const int r1 = ei[g * EPG + i1] - gb, c1 = ei[NEDGE + g * EPG + i1] - gb;
    rl[i0] = (unsigned char)r0; cl[i0] = (unsigned char)c0;
    rl[i1] = (unsigned char)r1; cl[i1] = (unsigned char)c1;
    atomicAdd(&cnt[c0], 1);
    atomicAdd(&cnt[c1], 1);

    for (int idx = t; idx < NPG * HIDN; idx += 256) {
        int n = idx >> 7, k = idx & 127;
        const float* xr = x + (g * NPG + n) * 65;
        float v = (k < DINF) ? xr[k] : emb[((int)xr[64]) * DINF + (k - DINF)];
        A[n * LDH + k] = v;
    }
    if (t < 3 * DINF) wih_s[t] = Wih[t];
    __syncthreads();

    // ---- dinv + exclusive prefix scan of cnt (wave 0, shfl scan) ----
    if (t < NPG) {
        int d = cnt[t];
        dinv[t] = rsqrtf((float)(d + 1));  // +1 self loop
        int s = d;
#pragma unroll
        for (int o = 1; o < 64; o <<= 1) {
            int u = __shfl_up(s, o, 64);
            if (t >= o) s += u;
        }
        off[t + 1] = s;
        if (t == 0) off[0] = 0;
    }
    __syncthreads();

    // ---- parallel CSR fill (order within a node arbitrary: fp-sum reorder only) ----
    {
        int p0 = off[c0] + atomicAdd(&cnt2[c0], 1);
        srl[p0] = (unsigned char)r0;
        snorm[p0] = dinv[r0] * dinv[c0];
        int p1 = off[c1] + atomicAdd(&cnt2[c1], 1);
        srl[p1] = (unsigned char)r1;
        snorm[p1] = dinv[r1] * dinv[c1];
    }
    __syncthreads();

    gcn_layer(A, srl, snorm, dinv, off, (const float4*)W1, b1, t);
    gcn_layer(A, srl, snorm, dinv, off, (const float4*)W2, b2, t);
    gcn_layer(A, srl, snorm, dinv, off, (const float4*)W3, b3, t);

    // ---- fc: hfc = gelu(h3 @ fcW + fcb) -> A as [64][LDF] (in-place) ----
    {
        const float4* FW4 = (const float4*)fcW;
        const int fq = t & 15;   // f = 4*fq, 0..63
        const int n0 = t >> 4;   // 0..15 ; nodes n0 + 16j
        float4 fa[4];
#pragma unroll
        for (int j = 0; j < 4; ++j) fa[j] = make_float4(0.f, 0.f, 0.f, 0.f);
#pragma unroll 2
        for (int k0 = 0; k0 < HIDN; k0 += 4) {
            float4 w0 = FW4[(k0 + 0) * 16 + fq];
            float4 w1 = FW4[(k0 + 1) * 16 + fq];
            float4 w2 = FW4[(k0 + 2) * 16 + fq];
            float4 w3 = FW4[(k0 + 3) * 16 + fq];
#pragma unroll
            for (int j = 0; j < 4; ++j) {
                float4 h4 = *(const float4*)&A[(n0 + 16 * j) * LDH + k0];
                fa[j].x = fmaf(h4.x, w0.x, fa[j].x);
                fa[j].y = fmaf(h4.x, w0.y, fa[j].y);
                fa[j].z = fmaf(h4.x, w0.z, fa[j].z);
                fa[j].w = fmaf(h4.x, w0.w, fa[j].w);
                fa[j].x = fmaf(h4.y, w1.x, fa[j].x);
                fa[j].y = fmaf(h4.y, w1.y, fa[j].y);
                fa[j].z = fmaf(h4.y, w1.z, fa[j].z);
                fa[j].w = fmaf(h4.y, w1.w, fa[j].w);
                fa[j].x = fmaf(h4.z, w2.x, fa[j].x);
                fa[j].y = fmaf(h4.z, w2.y, fa[j].y);
                fa[j].z = fmaf(h4.z, w2.z, fa[j].z);
                fa[j].w = fmaf(h4.z, w2.w, fa[j].w);
                fa[j].x = fmaf(h4.w, w3.x, fa[j].x);
                fa[j].y = fmaf(h4.w, w3.y, fa[j].y);
                fa[j].z = fmaf(h4.w, w3.z, fa[j].z);
                fa[j].w = fmaf(h4.w, w3.w, fa[j].w);
            }
        }
        __syncthreads();   // all reads of h3 done; safe to overwrite A
        float4 fb = *(const float4*)&fcb[4 * fq];
#pragma unroll
        for (int j = 0; j < 4; ++j) {
            int n = n0 + 16 * j;
            A[n * LDF + 4 * fq + 0] = gelu_exact(fa[j].x + fb.x);
            A[n * LDF + 4 * fq + 1] = gelu_exact(fa[j].y + fb.y);
            A[n * LDF + 4 * fq + 2] = gelu_exact(fa[j].z + fb.z);
            A[n * LDF + 4 * fq + 3] = gelu_exact(fa[j].w + fb.w);
        }
    }
    __syncthreads();

    // ---- per-edge GRU input: gi = (0.5*(h[r]+h[c])) @ Wih^T + bih ----
    {
        const float bi0 = bih[0], bi1 = bih[1], bi2 = bih[2];
#pragma unroll
        for (int rep = 0; rep < 2; ++rep) {
            int i = t + rep * 256;
            int r = rl[i], c = cl[i];
            const float* hr = &A[r * LDF];
            const float* hc = &A[c * LDF];
            float a0 = 0.f, a1 = 0.f, a2 = 0.f;
#pragma unroll 4
            for (int k = 0; k < DINF; ++k) {
                float xk = 0.5f * (hr[k] + hc[k]);
                a0 = fmaf(xk, wih_s[k], a0);
                a1 = fmaf(xk, wih_s[DINF + k], a1);
                a2 = fmaf(xk, wih_s[2 * DINF + k], a2);
            }
            gi4[g * EPG + i] = make_float4(a0 + bi0, a1 + bi1, a2 + bi2, 0.f);
        }
    }
}

__device__ __forceinline__ float gru_step(float h, float4 gi,
    float wr, float wz, float wn, float br, float bz, float bn)
{
    float r = fast_sigmoid(gi.x + fmaf(h, wr, br));
    float z = fast_sigmoid(gi.y + fmaf(h, wz, bz));
    float n = fast_tanh(fmaf(r, fmaf(h, wn, bn), gi.z));
    return fmaf(z, h - n, n);   // (1-z)*n + z*h
}

// 2 independent chains per thread: ILP breaks the dependent-latency bound.
__global__ __launch_bounds__(64) void gru_scan(
    const float4* __restrict__ gi4,
    const float* __restrict__ Whh, const float* __restrict__ bhh,
    const float* __restrict__ init_hs, float* __restrict__ out)
{
    const int tid = blockIdx.x * 64 + threadIdx.x;   // 0..511
    const float wr = Whh[0], wz = Whh[1], wn = Whh[2];
    const float br = bhh[0], bz = bhh[1], bn = bhh[2];
    const float h0i = init_hs[0];

    float h[2] = { h0i, h0i };
    float ssum[2] = { 0.f, 0.f }, lastval[2] = { 0.f, 0.f }, firstval[2] = { 0.f, 0.f };
    int lastidx[2] = { -1, -1 };
    const int gg[2] = { tid, tid + 512 };
    const float4* gp0 = gi4 + (size_t)gg[0] * EPG;
    const float4* gp1 = gi4 + (size_t)gg[1] * EPG;
    float* flat0 = out + NG + (size_t)gg[0] * EPG;
    float* flat1 = out + NG + (size_t)gg[1] * EPG;

    float4 a0 = gp0[0], a1 = gp0[1], a2 = gp0[2], a3 = gp0[3];
    float4 b0 = gp1[0], b1 = gp1[1], b2 = gp1[2], b3 = gp1[3];
    for (int tt = 0; tt < EPG; tt += 4) {
        float4 pa0, pa1, pa2, pa3, pb0, pb1, pb2, pb3;
        if (tt + 4 < EPG) {
            pa0 = gp0[tt + 4]; pa1 = gp0[tt + 5]; pa2 = gp0[tt + 6]; pa3 = gp0[tt + 7];
            pb0 = gp1[tt + 4]; pb1 = gp1[tt + 5]; pb2 = gp1[tt + 6]; pb3 = gp1[tt + 7];
        } else {
            pa0 = a0; pa1 = a1; pa2 = a2; pa3 = a3;
            pb0 = b0; pb1 = b1; pb2 = b2; pb3 = b3;
        }
        float4 hqa, hqb;
        h[0] = gru_step(h[0], a0, wr, wz, wn, br, bz, bn); hqa.x = h[0];
        h[1] = gru_step(h[1], b0, wr, wz, wn, br, bz, bn); hqb.x = h[1];
        h[0] = gru_step(h[0], a1, wr, wz, wn, br, bz, bn); hqa.y = h[0];
        h[1] = gru_step(h[1], b1, wr, wz, wn, br, bz, bn); hqb.y = h[1];
        h[0] = gru_step(h[0], a2, wr, wz, wn, br, bz, bn); hqa.z = h[0];
        h[1] = gru_step(h[1], b2, wr, wz, wn, br, bz, bn); hqb.z = h[1];
        h[0] = gru_step(h[0], a3, wr, wz, wn, br, bz, bn); hqa.w = h[0];
        h[1] = gru_step(h[1], b3, wr, wz, wn, br, bz, bn); hqb.w = h[1];
        *(float4*)&flat0[tt] = hqa;
        *(float4*)&flat1[tt] = hqb;
        if (tt == 0) { firstval[0] = hqa.x; firstval[1] = hqb.x; }
        ssum[0] += ((hqa.x + hqa.y) + (hqa.z + hqa.w));
        ssum[1] += ((hqb.x + hqb.y) + (hqb.z + hqb.w));
        if (hqa.x != 0.f) { lastidx[0] = tt;     lastval[0] = hqa.x; }
        if (hqa.y != 0.f) { lastidx[0] = tt + 1; lastval[0] = hqa.y; }
        if (hqa.z != 0.f) { lastidx[0] = tt + 2; lastval[0] = hqa.z; }
        if (hqa.w != 0.f) { lastidx[0] = tt + 3; lastval[0] = hqa.w; }
        if (hqb.x != 0.f) { lastidx[1] = tt;     lastval[1] = hqb.x; }
        if (hqb.y != 0.f) { lastidx[1] = tt + 1; lastval[1] = hqb.y; }
        if (hqb.z != 0.f) { lastidx[1] = tt + 2; lastval[1] = hqb.z; }
        if (hqb.w != 0.f) { lastidx[1] = tt + 3; lastval[1] = hqb.w; }
        a0 = pa0; a1 = pa1; a2 = pa2; a3 = pa3;
        b0 = pb0; b1 = pb1; b2 = pb2; b3 = pb3;
    }
    out[gg[0]] = (ssum[0] > 0.f && lastidx[0] >= 0) ? lastval[0] : firstval[0];
    out[gg[1]] = (ssum[1] > 0.f && lastidx[1] >= 0) ? lastval[1] : firstval[1];
}

extern "C" void kernel_launch(void* const* d_in, const int* in_sizes, int n_in,
                              void* d_out, int out_size, void* d_ws, size_t ws_size,
                              hipStream_t stream) {
    const float* x    = (const float*)d_in[0];
    const float* emb  = (const float*)d_in[1];
    const float* W1   = (const float*)d_in[2];
    const float* b1   = (const float*)d_in[3];
    const float* W2   = (const float*)d_in[4];
    const float* b2   = (const float*)d_in[5];
    const float* W3   = (const float*)d_in[6];
    const float* b3   = (const float*)d_in[7];
    const float* fcW  = (const float*)d_in[8];
    const float* fcb  = (const float*)d_in[9];
    const float* Wih  = (const float*)d_in[10];
    const float* Whh  = (const float*)d_in[11];
    const float* bih  = (const float*)d_in[12];
    const float* bhh  = (const float*)d_in[13];
    const float* ihs  = (const float*)d_in[14];
    const int*   ei   = (const int*)d_in[15];
    float* out = (float*)d_out;
    float4* gi4 = (float4*)d_ws;   // [NEDGE] float4 = 8 MB scratch

    fused_graph<<<dim3(NG), dim3(256), 0, stream>>>(
        x, emb, W1, b1, W2, b2, W3, b3, fcW, fcb, Wih, bih, ei, gi4);
    gru_scan<<<dim3(8), dim3(64), 0, stream>>>(gi4, Whh, bhh, ihs, out);
}

// Round 3
// 138.707 us; speedup vs baseline: 2.1885x; 1.6343x over previous
//
#include <hip/hip_runtime.h>
#include <math.h>

#define NG    1024
#define NPG   64
#define EPG   512
#define NEDGE 524288
#define HIDN  128
#define DINF  64

typedef __attribute__((ext_vector_type(8))) short short8b;   // 8 x bf16 (4 VGPR)
typedef __attribute__((ext_vector_type(4))) float f32x4;

__device__ __forceinline__ float gelu_exact(float v) {
    return 0.5f * v * (1.0f + erff(v * 0.70710678118654752440f));
}
__device__ __forceinline__ void split_bf16(float v, short& hi, short& lo) {
    unsigned u = __builtin_bit_cast(unsigned, v);
    hi = (short)(u >> 16);
    float hif = __builtin_bit_cast(float, u & 0xffff0000u);
    lo = (short)(__builtin_bit_cast(unsigned, v - hif) >> 16);
}

// ---- LDS layouts (short-element index), chunk(8 bf16 = 16B)-XOR-swizzled ----
// h: [64 m][128 k]
__device__ __forceinline__ int hidx(int m, int k) {
    return m * 128 + (((k >> 3) ^ ((m & 7) << 1)) << 3) + (k & 7);
}
// hwT: [128 n(feat)][64 m(src)]
__device__ __forceinline__ int tidx(int n, int m) {
    return n * 64 + (((m >> 3) ^ (n & 7)) << 3) + (m & 7);
}
// S: [64 dst][64 src]
__device__ __forceinline__ int sidx(int m, int k) {
    return m * 64 + (((k >> 3) ^ (m & 7)) << 3) + (k & 7);
}

// One GCN layer: h(LDS bf16 hi/lo) @ W(global bf16 hi/lo, [n][k]) -> acc
// -> hwT (bf16 hi/lo, over h region) -> S @ hwT -> gelu(+b) -> new h.
__device__ __forceinline__ void gcn_layer_mfma(
    short* Hh, short* Hl,
    const short* Sh, const short* Sl,
    const short* __restrict__ Wh, const short* __restrict__ Wl,
    const float* __restrict__ bb, int t)
{
    const int l = t & 63;
    const int l15 = l & 15, lk = l >> 4;
    const int nb = (t >> 6) * 32;          // wave owns feats [nb, nb+32)

    // ---- GEMM: hw = h @ W  (M=64, N=128 split 32/wave, K=128) ----
    f32x4 acc[4][2];
#pragma unroll
    for (int mt = 0; mt < 4; ++mt)
#pragma unroll
        for (int nt = 0; nt < 2; ++nt) acc[mt][nt] = (f32x4){0.f, 0.f, 0.f, 0.f};

#pragma unroll
    for (int k0 = 0; k0 < 128; k0 += 32) {
        const int kk = k0 + lk * 8;
        short8b bh[2], bl[2];
#pragma unroll
        for (int nt = 0; nt < 2; ++nt) {
            int n = nb + nt * 16 + l15;
            bh[nt] = *(const short8b*)&Wh[n * 128 + kk];
            bl[nt] = *(const short8b*)&Wl[n * 128 + kk];
        }
#pragma unroll
        for (int mt = 0; mt < 4; ++mt) {
            int id = hidx(mt * 16 + l15, kk);
            short8b ah = *(const short8b*)&Hh[id];
            short8b al = *(const short8b*)&Hl[id];
#pragma unroll
            for (int nt = 0; nt < 2; ++nt) {
                acc[mt][nt] = __builtin_amdgcn_mfma_f32_16x16x32_bf16(ah, bh[nt], acc[mt][nt], 0, 0, 0);
                acc[mt][nt] = __builtin_amdgcn_mfma_f32_16x16x32_bf16(ah, bl[nt], acc[mt][nt], 0, 0, 0);
                acc[mt][nt] = __builtin_amdgcn_mfma_f32_16x16x32_bf16(al, bh[nt], acc[mt][nt], 0, 0, 0);
            }
        }
    }
    __syncthreads();   // all h reads done; safe to overwrite with hwT

    // ---- write hw^T as bf16 hi/lo into the h region ----
#pragma unroll
    for (int mt = 0; mt < 4; ++mt)
#pragma unroll
        for (int nt = 0; nt < 2; ++nt)
#pragma unroll
            for (int r = 0; r < 4; ++r) {
                int msrc = mt * 16 + lk * 4 + r;     // D row = src node
                int n = nb + nt * 16 + l15;          // D col = feat
                short hi, lo; split_bf16(acc[mt][nt][r], hi, lo);
                int id = tidx(n, msrc);
                Hh[id] = hi; Hl[id] = lo;
            }
    __syncthreads();   // hwT ready

    // ---- AGG: S @ hwT  (M=64 dst, N=128 feats, K=64 src) ----
    f32x4 a2[4][2];
#pragma unroll
    for (int mt = 0; mt < 4; ++mt)
#pragma unroll
        for (int nt = 0; nt < 2; ++nt) a2[mt][nt] = (f32x4){0.f, 0.f, 0.f, 0.f};

#pragma unroll
    for (int k0 = 0; k0 < 64; k0 += 32) {
        const int kk = k0 + lk * 8;
        short8b bh[2], bl[2];
#pragma unroll
        for (int nt = 0; nt < 2; ++nt) {
            int n = nb + nt * 16 + l15;
            int id = tidx(n, kk);
            bh[nt] = *(const short8b*)&Hh[id];
            bl[nt] = *(const short8b*)&Hl[id];
        }
#pragma unroll
        for (int mt = 0; mt < 4; ++mt) {
            int id = sidx(mt * 16 + l15, kk);
            short8b ah = *(const short8b*)&Sh[id];
            short8b al = *(const short8b*)&Sl[id];
#pragma unroll
            for (int nt = 0; nt < 2; ++nt) {
                a2[mt][nt] = __builtin_amdgcn_mfma_f32_16x16x32_bf16(ah, bh[nt], a2[mt][nt], 0, 0, 0);
                a2[mt][nt] = __builtin_amdgcn_mfma_f32_16x16x32_bf16(ah, bl[nt], a2[mt][nt], 0, 0, 0);
                a2[mt][nt] = __builtin_amdgcn_mfma_f32_16x16x32_bf16(al, bh[nt], a2[mt][nt], 0, 0, 0);
            }
        }
    }
    __syncthreads();   // hwT reads done; safe to overwrite with new h

    // ---- bias + exact gelu -> new h (bf16 hi/lo, h layout) ----
#pragma unroll
    for (int nt = 0; nt < 2; ++nt) {
        int n = nb + nt * 16 + l15;
        float bv = bb[n];
#pragma unroll
        for (int mt = 0; mt < 4; ++mt)
#pragma unroll
            for (int r = 0; r < 4; ++r) {
                int m = mt * 16 + lk * 4 + r;        // dst node
                float v = gelu_exact(a2[mt][nt][r] + bv);
                short hi, lo; split_bf16(v, hi, lo);
                int id = hidx(m, n);
                Hh[id] = hi; Hl[id] = lo;
            }
    }
    __syncthreads();
}

__global__ __launch_bounds__(256, 3) void fused_graph(
    const float* __restrict__ x, const float* __restrict__ emb,
    const float* __restrict__ b1, const float* __restrict__ b2,
    const float* __restrict__ b3, const float* __restrict__ fcb,
    const float* __restrict__ Wih, const float* __restrict__ bih,
    const float* __restrict__ bhh,
    const int* __restrict__ ei, const short* __restrict__ wt,
    float* __restrict__ grc, float* __restrict__ gzc, float* __restrict__ gnc)
{
    __shared__ __align__(16) char Ubuf[32768];   // {Hh|Hl} <-> {hwT} <-> fcout[64][65]
    __shared__ __align__(16) char Sbuf[16384];   // S32 build -> {Sh|Sl}
    __shared__ unsigned char rl[EPG], cl[EPG];
    __shared__ float wih_s[3 * DINF];
    __shared__ float dinv[NPG];
    __shared__ int cnt[NPG];

    short* Hh = (short*)Ubuf;
    short* Hl = (short*)(Ubuf + 16384);
    float* fcout = (float*)Ubuf;
    float* S32 = (float*)Sbuf;
    short* Sh = (short*)Sbuf;
    short* Sl = (short*)(Sbuf + 8192);

    const int g = blockIdx.x;
    const int t = threadIdx.x;

    if (t < NPG) cnt[t] = 0;
#pragma unroll
    for (int j = 0; j < 16; ++j) S32[t + 256 * j] = 0.f;
    __syncthreads();

    // ---- edges (2/thread) + in-degree; stage h0 bf16 hi/lo ----
    const int gb = g * NPG;
    const int i0 = t, i1 = t + 256;
    const int r0 = ei[g * EPG + i0] - gb, c0 = ei[NEDGE + g * EPG + i0] - gb;
    const int r1 = ei[g * EPG + i1] - gb, c1 = ei[NEDGE + g * EPG + i1] - gb;
    rl[i0] = (unsigned char)r0; cl[i0] = (unsigned char)c0;
    rl[i1] = (unsigned char)r1; cl[i1] = (unsigned char)c1;
    atomicAdd(&cnt[c0], 1);
    atomicAdd(&cnt[c1], 1);

#pragma unroll
    for (int rep = 0; rep < 32; ++rep) {
        int idx = t + rep * 256;                  // 8192 = 64 x 128
        int n = idx >> 7, k = idx & 127;
        const float* xr = x + (g * NPG + n) * 65;
        float v = (k < DINF) ? xr[k] : emb[((int)xr[64]) * DINF + (k - DINF)];
        short hi, lo; split_bf16(v, hi, lo);
        int id = hidx(n, k);
        Hh[id] = hi; Hl[id] = lo;
    }
    if (t < 3 * DINF) wih_s[t] = Wih[t];
    __syncthreads();

    if (t < NPG) dinv[t] = rsqrtf((float)(cnt[t] + 1));   // +1 self loop
    __syncthreads();

    // ---- dense normalized adjacency S[dst][src] (handles duplicate edges) ----
    atomicAdd(&S32[c0 * 64 + r0], dinv[r0] * dinv[c0]);
    atomicAdd(&S32[c1 * 64 + r1], dinv[r1] * dinv[c1]);
    if (t < NPG) atomicAdd(&S32[t * 64 + t], dinv[t] * dinv[t]);
    __syncthreads();

    // ---- convert S fp32 -> bf16 hi/lo in place ----
    float sv[16];
#pragma unroll
    for (int j = 0; j < 16; ++j) sv[j] = S32[t + 256 * j];
    __syncthreads();
#pragma unroll
    for (int j = 0; j < 16; ++j) {
        int e = t + 256 * j;
        int m = e >> 6, k = e & 63;
        short hi, lo; split_bf16(sv[j], hi, lo);
        int id = sidx(m, k);
        Sh[id] = hi; Sl[id] = lo;
    }
    __syncthreads();

    gcn_layer_mfma(Hh, Hl, Sh, Sl, wt,          wt + 16384, b1, t);
    gcn_layer_mfma(Hh, Hl, Sh, Sl, wt + 32768,  wt + 49152, b2, t);
    gcn_layer_mfma(Hh, Hl, Sh, Sl, wt + 65536,  wt + 81920, b3, t);

    // ---- fc: gelu(h3 @ fcW + fcb) -> fcout[64][65] fp32 ----
    {
        const short* Fh = wt + 98304;
        const short* Fl = wt + 106496;
        const int l = t & 63;
        const int l15 = l & 15, lk = l >> 4;
        const int nb = (t >> 6) * 16;            // wave owns 16 of 64 cols
        f32x4 fa[4];
#pragma unroll
        for (int mt = 0; mt < 4; ++mt) fa[mt] = (f32x4){0.f, 0.f, 0.f, 0.f};
#pragma unroll
        for (int k0 = 0; k0 < 128; k0 += 32) {
            const int kk = k0 + lk * 8;
            int n = nb + l15;
            short8b bh = *(const short8b*)&Fh[n * 128 + kk];
            short8b bl = *(const short8b*)&Fl[n * 128 + kk];
#pragma unroll
            for (int mt = 0; mt < 4; ++mt) {
                int id = hidx(mt * 16 + l15, kk);
                short8b ah = *(const short8b*)&Hh[id];
                short8b al = *(const short8b*)&Hl[id];
                fa[mt] = __builtin_amdgcn_mfma_f32_16x16x32_bf16(ah, bh, fa[mt], 0, 0, 0);
                fa[mt] = __builtin_amdgcn_mfma_f32_16x16x32_bf16(ah, bl, fa[mt], 0, 0, 0);
                fa[mt] = __builtin_amdgcn_mfma_f32_16x16x32_bf16(al, bh, fa[mt], 0, 0, 0);
            }
        }
        __syncthreads();   // h3 reads done; fcout overwrites the region
        int n = nb + l15;
        float fb = fcb[n];
#pragma unroll
        for (int mt = 0; mt < 4; ++mt)
#pragma unroll
            for (int r = 0; r < 4; ++r) {
                int m = mt * 16 + lk * 4 + r;
                fcout[m * 65 + n] = gelu_exact(fa[mt][r] + fb);
            }
    }
    __syncthreads();

    // ---- per-edge GRU gate constants (pre-scaled for the scan kernel) ----
    {
        const float L2E = 1.4426950408889634f;
        const float bi0 = bih[0], bi1 = bih[1], bi2 = bih[2];
        const float bh0 = bhh[0], bh1 = bhh[1];
#pragma unroll
        for (int rep = 0; rep < 2; ++rep) {
            int i = t + rep * 256;
            int r = rl[i], c = cl[i];
            const float* hr = &fcout[r * 65];
            const float* hc = &fcout[c * 65];
            float a0 = 0.f, a1 = 0.f, a2v = 0.f;
#pragma unroll 4
            for (int k = 0; k < DINF; ++k) {
                float xk = 0.5f * (hr[k] + hc[k]);
                a0 = fmaf(xk, wih_s[k], a0);
                a1 = fmaf(xk, wih_s[DINF + k], a1);
                a2v = fmaf(xk, wih_s[2 * DINF + k], a2v);
            }
            size_t p = (size_t)g * EPG + i;
            grc[p] = -L2E * (a0 + bi0 + bh0);
            gzc[p] = -L2E * (a1 + bi1 + bh1);
            gnc[p] = 2.f * L2E * (a2v + bi2);
        }
    }
}

// ---- weight pre-transpose/convert: W[k][n] -> Wt_hi/lo[n][k] bf16 ----
__global__ __launch_bounds__(256) void conv_weights(
    const float* __restrict__ W1, const float* __restrict__ W2,
    const float* __restrict__ W3, const float* __restrict__ fcW,
    short* __restrict__ wt)
{
    int tid = blockIdx.x * 256 + threadIdx.x;
    if (tid < 49152) {
        int L = tid >> 14, e = tid & 16383;
        const float* W = (L == 0) ? W1 : (L == 1) ? W2 : W3;
        float v = W[e];                  // e = k*128 + n (coalesced read)
        int k = e >> 7, n = e & 127;
        short hi, lo; split_bf16(v, hi, lo);
        wt[L * 32768 + n * 128 + k] = hi;
        wt[L * 32768 + 16384 + n * 128 + k] = lo;
    } else if (tid < 57344) {
        int e = tid - 49152;
        float v = fcW[e];                // e = k*64 + n
        int k = e >> 6, n = e & 63;
        short hi, lo; split_bf16(v, hi, lo);
        wt[98304 + n * 128 + k] = hi;
        wt[106496 + n * 128 + k] = lo;
    }
}

// ---- GRU scan: 1 thread per graph, latency-minimized step ----
__global__ __launch_bounds__(64) void gru_scan(
    const float* __restrict__ grc, const float* __restrict__ gzc,
    const float* __restrict__ gnc,
    const float* __restrict__ Whh, const float* __restrict__ bhh,
    const float* __restrict__ init_hs, float* __restrict__ out)
{
    const int g = blockIdx.x * 64 + threadIdx.x;    // 0..1023
    const float L2E = 1.4426950408889634f;
    const float wrc = -L2E * Whh[0];
    const float wzc = -L2E * Whh[1];
    const float wnc2 = 2.f * L2E * Whh[2];
    const float bnc2 = 2.f * L2E * bhh[2];
    const float* pr = grc + (size_t)g * EPG;
    const float* pz = gzc + (size_t)g * EPG;
    const float* pn = gnc + (size_t)g * EPG;
    float* flat = out + NG + (size_t)g * EPG;

    float h = init_hs[0];
    float ssum = 0.f, lastval = 0.f, firstval = 0.f;
    int lastidx = -1;

    float cr[4], cz[4], cn[4];
#pragma unroll
    for (int s = 0; s < 4; ++s) { cr[s] = pr[s]; cz[s] = pz[s]; cn[s] = pn[s]; }

    for (int tt = 0; tt < EPG; tt += 4) {
        float nr[4], nz[4], nn[4];
        if (tt + 4 < EPG) {
#pragma unroll
            for (int s = 0; s < 4; ++s) {
                nr[s] = pr[tt + 4 + s]; nz[s] = pz[tt + 4 + s]; nn[s] = pn[tt + 4 + s];
            }
        } else {
#pragma unroll
            for (int s = 0; s < 4; ++s) { nr[s] = cr[s]; nz[s] = cz[s]; nn[s] = cn[s]; }
        }
        float4 hq;
#pragma unroll
        for (int s = 0; s < 4; ++s) {
            float ur = fmaf(h, wrc, cr[s]);                       // -log2e * gate_r
            float uz = fmaf(h, wzc, cz[s]);
            float hn = fmaf(h, wnc2, bnc2);                       // 2log2e*(h*wn+bn)
            float r = __builtin_amdgcn_rcpf(1.f + __builtin_amdgcn_exp2f(ur));
            float z = __builtin_amdgcn_rcpf(1.f + __builtin_amdgcn_exp2f(uz));
            float xn = fmaf(r, hn, cn[s]);                        // 2log2e * n_arg
            float q = __builtin_amdgcn_rcpf(1.f + __builtin_amdgcn_exp2f(xn));
            float A = 1.f - z;
            float C = fmaf(z, h, A);
            float m2A = -2.f * A;
            h = fmaf(q, m2A, C);       // (1-2q)(1-z) + z*h
            ((float*)&hq)[s] = h;
        }
        *(float4*)&flat[tt] = hq;
        if (tt == 0) firstval = hq.x;
        ssum += ((hq.x + hq.y) + (hq.z + hq.w));
        if (hq.x != 0.f) { lastidx = tt;     lastval = hq.x; }
        if (hq.y != 0.f) { lastidx = tt + 1; lastval = hq.y; }
        if (hq.z != 0.f) { lastidx = tt + 2; lastval = hq.z; }
        if (hq.w != 0.f) { lastidx = tt + 3; lastval = hq.w; }
#pragma unroll
        for (int s = 0; s < 4; ++s) { cr[s] = nr[s]; cz[s] = nz[s]; cn[s] = nn[s]; }
    }
    out[g] = (ssum > 0.f && lastidx >= 0) ? lastval : firstval;
}

extern "C" void kernel_launch(void* const* d_in, const int* in_sizes, int n_in,
                              void* d_out, int out_size, void* d_ws, size_t ws_size,
                              hipStream_t stream) {
    const float* x    = (const float*)d_in[0];
    const float* emb  = (const float*)d_in[1];
    const float* W1   = (const float*)d_in[2];
    const float* b1   = (const float*)d_in[3];
    const float* W2   = (const float*)d_in[4];
    const float* b2   = (const float*)d_in[5];
    const float* W3   = (const float*)d_in[6];
    const float* b3   = (const float*)d_in[7];
    const float* fcW  = (const float*)d_in[8];
    const float* fcb  = (const float*)d_in[9];
    const float* Wih  = (const float*)d_in[10];
    const float* Whh  = (const float*)d_in[11];
    const float* bih  = (const float*)d_in[12];
    const float* bhh  = (const float*)d_in[13];
    const float* ihs  = (const float*)d_in[14];
    const int*   ei   = (const int*)d_in[15];
    float* out = (float*)d_out;

    // workspace: [0,2MB) grc | [2,4MB) gzc | [4,6MB) gnc | [6MB, +224KB) weights bf16
    float* grc = (float*)d_ws;
    float* gzc = (float*)((char*)d_ws + (2u << 20));
    float* gnc = (float*)((char*)d_ws + (4u << 20));
    short* wt  = (short*)((char*)d_ws + (6u << 20));

    conv_weights<<<dim3(224), dim3(256), 0, stream>>>(W1, W2, W3, fcW, wt);
    fused_graph<<<dim3(NG), dim3(256), 0, stream>>>(
        x, emb, b1, b2, b3, fcb, Wih, bih, bhh, ei, wt, grc, gzc, gnc);
    gru_scan<<<dim3(16), dim3(64), 0, stream>>>(grc, gzc, gnc, Whh, bhh, ihs, out);
}

// Round 4
// 117.673 us; speedup vs baseline: 2.5797x; 1.1787x over previous
//
#include <hip/hip_runtime.h>
#include <math.h>

#define NG    1024
#define NPG   64
#define EPG   512
#define NEDGE 524288
#define DINF  64

typedef __attribute__((ext_vector_type(8))) short short8b;   // 8 x bf16 (4 VGPR)
typedef __attribute__((ext_vector_type(4))) short short4b;   // 4 x bf16 (2 VGPR)
typedef __attribute__((ext_vector_type(4))) float f32x4;

__device__ __forceinline__ float gelu_exact(float v) {
    return 0.5f * v * (1.0f + erff(v * 0.70710678118654752440f));
}
__device__ __forceinline__ void split_bf16(float v, short& hi, short& lo) {
    unsigned u = __builtin_bit_cast(unsigned, v);
    hi = (short)(u >> 16);
    float hif = __builtin_bit_cast(float, u & 0xffff0000u);
    lo = (short)(__builtin_bit_cast(unsigned, v - hif) >> 16);
}

// ---- LDS layouts (short-element index), 8-short(16B)-chunk XOR-swizzled ----
__device__ __forceinline__ int hidx(int m, int k) {   // h[64 node][128 feat]
    return m * 128 + (((k >> 3) ^ (m & 15)) << 3) + (k & 7);
}
__device__ __forceinline__ int tidx(int f, int m) {   // hwT[128 feat][64 node]
    return f * 64 + (((m >> 3) ^ (f & 7)) << 3) + (m & 7);
}
__device__ __forceinline__ int sidx(int m, int k) {   // S[64 dst][64 src]
    return m * 64 + (((k >> 3) ^ (m & 7)) << 3) + (k & 7);
}

// One GCN layer. 3 barriers:
//  [GEMM reads h] bar [hwT b64-write; AGG reads own-wave hwT + S] bar [h b64-write] bar
__device__ __forceinline__ void gcn_layer_mfma(
    short* Hh, short* Hl, const short* Sh, const short* Sl,
    const short* __restrict__ Wh, const short* __restrict__ Wl,
    const float* __restrict__ bb, int t)
{
    const int l15 = t & 15, lk = (t >> 4) & 3, w = t >> 6;
    const int nb = w * 32;          // wave owns feats [nb, nb+32)

    // ---- GEMM: hw[node][feat] = h @ W  (M=64, N=128 (32/wave), K=128) ----
    f32x4 acc[4][2];
#pragma unroll
    for (int mt = 0; mt < 4; ++mt)
#pragma unroll
        for (int nt = 0; nt < 2; ++nt) acc[mt][nt] = (f32x4){0.f, 0.f, 0.f, 0.f};

    __builtin_amdgcn_s_setprio(1);
#pragma unroll
    for (int k0 = 0; k0 < 128; k0 += 32) {
        const int kk = k0 + lk * 8;
        short8b bh[2], bl[2];
#pragma unroll
        for (int nt = 0; nt < 2; ++nt) {
            int n = nb + nt * 16 + l15;
            bh[nt] = *(const short8b*)&Wh[n * 128 + kk];
            bl[nt] = *(const short8b*)&Wl[n * 128 + kk];
        }
#pragma unroll
        for (int mt = 0; mt < 4; ++mt) {
            short8b ah = *(const short8b*)&Hh[hidx(mt * 16 + l15, kk)];
            short8b al = *(const short8b*)&Hl[hidx(mt * 16 + l15, kk)];
#pragma unroll
            for (int nt = 0; nt < 2; ++nt) {
                acc[mt][nt] = __builtin_amdgcn_mfma_f32_16x16x32_bf16(ah, bh[nt], acc[mt][nt], 0, 0, 0);
                acc[mt][nt] = __builtin_amdgcn_mfma_f32_16x16x32_bf16(ah, bl[nt], acc[mt][nt], 0, 0, 0);
                acc[mt][nt] = __builtin_amdgcn_mfma_f32_16x16x32_bf16(al, bh[nt], acc[mt][nt], 0, 0, 0);
            }
        }
    }
    __builtin_amdgcn_s_setprio(0);
    __syncthreads();   // all waves done reading h; region becomes hwT

    // ---- hwT[feat][node] b64 writes (4 consecutive nodes per lane) ----
#pragma unroll
    for (int mt = 0; mt < 4; ++mt)
#pragma unroll
        for (int nt = 0; nt < 2; ++nt) {
            int f = nb + nt * 16 + l15;
            short4b h4, l4;
#pragma unroll
            for (int r = 0; r < 4; ++r) {
                short hi, lo; split_bf16(acc[mt][nt][r], hi, lo);
                h4[r] = hi; l4[r] = lo;
            }
            int id = tidx(f, mt * 16 + lk * 4);
            *(short4b*)&Hh[id] = h4;
            *(short4b*)&Hl[id] = l4;
        }

    // ---- AGG (transposed): D2[feat][dst] = hwT @ S^T  (M=128 (32/wave), N=64, K=64) ----
    // A-frags read only this wave's own hwT rows -> no barrier needed above.
    f32x4 a2[2][4];
#pragma unroll
    for (int mt = 0; mt < 2; ++mt)
#pragma unroll
        for (int nt = 0; nt < 4; ++nt) a2[mt][nt] = (f32x4){0.f, 0.f, 0.f, 0.f};

    __builtin_amdgcn_s_setprio(1);
#pragma unroll
    for (int k0 = 0; k0 < 64; k0 += 32) {
        const int kk = k0 + lk * 8;
        short8b sb[4], sl2[4];
#pragma unroll
        for (int nt = 0; nt < 4; ++nt) {
            int d = nt * 16 + l15;
            sb[nt]  = *(const short8b*)&Sh[sidx(d, kk)];
            sl2[nt] = *(const short8b*)&Sl[sidx(d, kk)];
        }
#pragma unroll
        for (int mt = 0; mt < 2; ++mt) {
            int f = nb + mt * 16 + l15;
            short8b ah = *(const short8b*)&Hh[tidx(f, kk)];
            short8b al = *(const short8b*)&Hl[tidx(f, kk)];
#pragma unroll
            for (int nt = 0; nt < 4; ++nt) {
                a2[mt][nt] = __builtin_amdgcn_mfma_f32_16x16x32_bf16(ah, sb[nt],  a2[mt][nt], 0, 0, 0);
                a2[mt][nt] = __builtin_amdgcn_mfma_f32_16x16x32_bf16(ah, sl2[nt], a2[mt][nt], 0, 0, 0);
                a2[mt][nt] = __builtin_amdgcn_mfma_f32_16x16x32_bf16(al, sb[nt],  a2[mt][nt], 0, 0, 0);
            }
        }
    }
    __builtin_amdgcn_s_setprio(0);
    __syncthreads();   // all hwT/S reads done; region becomes new h

    // ---- new h[node][feat] = gelu(D2^T + b[feat]); b64 (4 consecutive feats) ----
#pragma unroll
    for (int mt = 0; mt < 2; ++mt) {
        int f0 = nb + mt * 16 + lk * 4;
        float4 bv = *(const float4*)&bb[f0];
#pragma unroll
        for (int nt = 0; nt < 4; ++nt) {
            int dst = nt * 16 + l15;
            short4b h4, l4;
            float v0 = gelu_exact(a2[mt][nt][0] + bv.x);
            float v1 = gelu_exact(a2[mt][nt][1] + bv.y);
            float v2 = gelu_exact(a2[mt][nt][2] + bv.z);
            float v3 = gelu_exact(a2[mt][nt][3] + bv.w);
            short hi, lo;
            split_bf16(v0, hi, lo); h4[0] = hi; l4[0] = lo;
            split_bf16(v1, hi, lo); h4[1] = hi; l4[1] = lo;
            split_bf16(v2, hi, lo); h4[2] = hi; l4[2] = lo;
            split_bf16(v3, hi, lo); h4[3] = hi; l4[3] = lo;
            int id = hidx(dst, f0);
            *(short4b*)&Hh[id] = h4;
            *(short4b*)&Hl[id] = l4;
        }
    }
    __syncthreads();
}

__global__ __launch_bounds__(256, 3) void fused_graph(
    const float* __restrict__ x, const float* __restrict__ emb,
    const float* __restrict__ b1, const float* __restrict__ b2,
    const float* __restrict__ b3, const float* __restrict__ fcb,
    const float* __restrict__ Wih, const float* __restrict__ bih,
    const float* __restrict__ bhh,
    const int* __restrict__ ei, const short* __restrict__ wt,
    float* __restrict__ grc, float* __restrict__ gzc, float* __restrict__ gnc)
{
    __shared__ __align__(16) char Ubuf[32768];   // {Hh|Hl} <-> hwT <-> fcout[64][68]
    __shared__ __align__(16) char Sbuf[16384];   // S32 -> {Sh|Sl}
    __shared__ unsigned char rl[EPG], cl[EPG];
    __shared__ float wih_s[3 * DINF];
    __shared__ float dinv[NPG];
    __shared__ int cnt[NPG];

    short* Hh = (short*)Ubuf;
    short* Hl = (short*)(Ubuf + 16384);
    float* fcout = (float*)Ubuf;
    float* S32 = (float*)Sbuf;
    short* Sh = (short*)Sbuf;
    short* Sl = (short*)(Sbuf + 8192);

    const int g = blockIdx.x;
    const int t = threadIdx.x;

    if (t < NPG) cnt[t] = 0;
#pragma unroll
    for (int j = 0; j < 16; ++j) S32[t + 256 * j] = 0.f;
    __syncthreads();

    // ---- edges (2/thread) + degree count; stage h0 as b128 chunks ----
    const int gb = g * NPG;
    const int i0 = t, i1 = t + 256;
    const int r0 = ei[g * EPG + i0] - gb, c0 = ei[NEDGE + g * EPG + i0] - gb;
    const int r1 = ei[g * EPG + i1] - gb, c1 = ei[NEDGE + g * EPG + i1] - gb;
    rl[i0] = (unsigned char)r0; cl[i0] = (unsigned char)c0;
    rl[i1] = (unsigned char)r1; cl[i1] = (unsigned char)c1;
    atomicAdd(&cnt[c0], 1);
    atomicAdd(&cnt[c1], 1);

#pragma unroll
    for (int rep = 0; rep < 4; ++rep) {
        int id = t + rep * 256;              // 1024 chunk tasks: n(64) x kc(16)
        int n = id >> 4, kc = id & 15;
        const float* xr = x + (g * NPG + n) * 65;
        float v[8];
        if (kc < 8) {
#pragma unroll
            for (int j = 0; j < 8; ++j) v[j] = xr[kc * 8 + j];
        } else {
            int nid = (int)xr[64];
            const float4* e4 = (const float4*)&emb[nid * DINF + (kc - 8) * 8];
            float4 va = e4[0], vb = e4[1];
            v[0] = va.x; v[1] = va.y; v[2] = va.z; v[3] = va.w;
            v[4] = vb.x; v[5] = vb.y; v[6] = vb.z; v[7] = vb.w;
        }
        short8b h8, l8;
#pragma unroll
        for (int j = 0; j < 8; ++j) {
            short hi, lo; split_bf16(v[j], hi, lo);
            h8[j] = hi; l8[j] = lo;
        }
        int idd = hidx(n, kc * 8);
        *(short8b*)&Hh[idd] = h8;
        *(short8b*)&Hl[idd] = l8;
    }
    if (t < 3 * DINF) wih_s[t] = Wih[t];
    __syncthreads();

    if (t < NPG) dinv[t] = rsqrtf((float)(cnt[t] + 1));   // +1 self loop
    __syncthreads();

    // ---- dense normalized adjacency S[dst][src] (duplicates accumulate) ----
    atomicAdd(&S32[c0 * 64 + r0], dinv[r0] * dinv[c0]);
    atomicAdd(&S32[c1 * 64 + r1], dinv[r1] * dinv[c1]);
    if (t < NPG) atomicAdd(&S32[t * 64 + t], dinv[t] * dinv[t]);
    __syncthreads();

    // ---- convert S fp32 -> bf16 hi/lo (aliased; regs + 2 barriers), b128 writes ----
    float sv[16];
#pragma unroll
    for (int cp = 0; cp < 2; ++cp) {
        int cid = 2 * t + cp, m = cid >> 3, kc = cid & 7;
#pragma unroll
        for (int j = 0; j < 8; ++j) sv[cp * 8 + j] = S32[m * 64 + kc * 8 + j];
    }
    __syncthreads();
#pragma unroll
    for (int cp = 0; cp < 2; ++cp) {
        int cid = 2 * t + cp, m = cid >> 3, kc = cid & 7;
        short8b h8, l8;
#pragma unroll
        for (int j = 0; j < 8; ++j) {
            short hi, lo; split_bf16(sv[cp * 8 + j], hi, lo);
            h8[j] = hi; l8[j] = lo;
        }
        int id = sidx(m, kc * 8);
        *(short8b*)&Sh[id] = h8;
        *(short8b*)&Sl[id] = l8;
    }
    __syncthreads();

    gcn_layer_mfma(Hh, Hl, Sh, Sl, wt,         wt + 16384, b1, t);
    gcn_layer_mfma(Hh, Hl, Sh, Sl, wt + 32768, wt + 49152, b2, t);
    gcn_layer_mfma(Hh, Hl, Sh, Sl, wt + 65536, wt + 81920, b3, t);

    // ---- fc: gelu(h3 @ fcW + fcb) -> fcout[64][68] fp32 ----
    {
        const short* Fh = wt + 98304;
        const short* Fl = wt + 106496;
        const int l15 = t & 15, lk = (t >> 4) & 3, w = t >> 6;
        const int nb2 = w * 16;
        f32x4 fa[4];
#pragma unroll
        for (int mt = 0; mt < 4; ++mt) fa[mt] = (f32x4){0.f, 0.f, 0.f, 0.f};
        __builtin_amdgcn_s_setprio(1);
#pragma unroll
        for (int k0 = 0; k0 < 128; k0 += 32) {
            const int kk = k0 + lk * 8;
            int n = nb2 + l15;
            short8b bhf = *(const short8b*)&Fh[n * 128 + kk];
            short8b blf = *(const short8b*)&Fl[n * 128 + kk];
#pragma unroll
            for (int mt = 0; mt < 4; ++mt) {
                short8b ah = *(const short8b*)&Hh[hidx(mt * 16 + l15, kk)];
                short8b al = *(const short8b*)&Hl[hidx(mt * 16 + l15, kk)];
                fa[mt] = __builtin_amdgcn_mfma_f32_16x16x32_bf16(ah, bhf, fa[mt], 0, 0, 0);
                fa[mt] = __builtin_amdgcn_mfma_f32_16x16x32_bf16(ah, blf, fa[mt], 0, 0, 0);
                fa[mt] = __builtin_amdgcn_mfma_f32_16x16x32_bf16(al, bhf, fa[mt], 0, 0, 0);
            }
        }
        __builtin_amdgcn_s_setprio(0);
        __syncthreads();   // h3 reads done; region becomes fcout
        int n = nb2 + l15;
        float fb = fcb[n];
#pragma unroll
        for (int mt = 0; mt < 4; ++mt)
#pragma unroll
            for (int r = 0; r < 4; ++r) {
                int m = mt * 16 + lk * 4 + r;
                fcout[m * 68 + n] = gelu_exact(fa[mt][r] + fb);
            }
    }
    __syncthreads();

    // ---- per-edge GRU gate constants (float4 path) ----
    {
        const float L2E = 1.4426950408889634f;
        const float bi0 = bih[0], bi1 = bih[1], bi2 = bih[2];
        const float bh0 = bhh[0], bh1 = bhh[1];
        int ra = rl[i0], ca = cl[i0], rb = rl[i1], cb = cl[i1];
        const float4* hra = (const float4*)&fcout[ra * 68];
        const float4* hca = (const float4*)&fcout[ca * 68];
        const float4* hrb = (const float4*)&fcout[rb * 68];
        const float4* hcb = (const float4*)&fcout[cb * 68];
        float4 ar0 = {0,0,0,0}, az0 = {0,0,0,0}, an0 = {0,0,0,0};
        float4 ar1 = {0,0,0,0}, az1 = {0,0,0,0}, an1 = {0,0,0,0};
#pragma unroll
        for (int i = 0; i < 16; ++i) {
            float4 wr = *(const float4*)&wih_s[i * 4];
            float4 wz = *(const float4*)&wih_s[DINF + i * 4];
            float4 wn = *(const float4*)&wih_s[2 * DINF + i * 4];
            float4 pa = hra[i], qa = hca[i], pb = hrb[i], qb = hcb[i];
            float4 x0, x1;
            x0.x = 0.5f * (pa.x + qa.x); x0.y = 0.5f * (pa.y + qa.y);
            x0.z = 0.5f * (pa.z + qa.z); x0.w = 0.5f * (pa.w + qa.w);
            x1.x = 0.5f * (pb.x + qb.x); x1.y = 0.5f * (pb.y + qb.y);
            x1.z = 0.5f * (pb.z + qb.z); x1.w = 0.5f * (pb.w + qb.w);
            ar0.x = fmaf(x0.x, wr.x, ar0.x); ar0.y = fmaf(x0.y, wr.y, ar0.y);
            ar0.z = fmaf(x0.z, wr.z, ar0.z); ar0.w = fmaf(x0.w, wr.w, ar0.w);
            az0.x = fmaf(x0.x, wz.x, az0.x); az0.y = fmaf(x0.y, wz.y, az0.y);
            az0.z = fmaf(x0.z, wz.z, az0.z); az0.w = fmaf(x0.w, wz.w, az0.w);
            an0.x = fmaf(x0.x, wn.x, an0.x); an0.y = fmaf(x0.y, wn.y, an0.y);
            an0.z = fmaf(x0.z, wn.z, an0.z); an0.w = fmaf(x0.w, wn.w, an0.w);
            ar1.x = fmaf(x1.x, wr.x, ar1.x); ar1.y = fmaf(x1.y, wr.y, ar1.y);
            ar1.z = fmaf(x1.z, wr.z, ar1.z); ar1.w = fmaf(x1.w, wr.w, ar1.w);
            az1.x = fmaf(x1.x, wz.x, az1.x); az1.y = fmaf(x1.y, wz.y, az1.y);
            az1.z = fmaf(x1.z, wz.z, az1.z); az1.w = fmaf(x1.w, wz.w, az1.w);
            an1.x = fmaf(x1.x, wn.x, an1.x); an1.y = fmaf(x1.y, wn.y, an1.y);
            an1.z = fmaf(x1.z, wn.z, an1.z); an1.w = fmaf(x1.w, wn.w, an1.w);
        }
        float a0 = (ar0.x + ar0.y) + (ar0.z + ar0.w);
        float a1 = (az0.x + az0.y) + (az0.z + az0.w);
        float a2v = (an0.x + an0.y) + (an0.z + an0.w);
        size_t p = (size_t)g * EPG + i0;
        grc[p] = -L2E * (a0 + bi0 + bh0);
        gzc[p] = -L2E * (a1 + bi1 + bh1);
        gnc[p] = 2.f * L2E * (a2v + bi2);
        a0 = (ar1.x + ar1.y) + (ar1.z + ar1.w);
        a1 = (az1.x + az1.y) + (az1.z + az1.w);
        a2v = (an1.x + an1.y) + (an1.z + an1.w);
        p = (size_t)g * EPG + i1;
        grc[p] = -L2E * (a0 + bi0 + bh0);
        gzc[p] = -L2E * (a1 + bi1 + bh1);
        gnc[p] = 2.f * L2E * (a2v + bi2);
    }
}

// ---- weight pre-transpose/convert: W[k][n] -> Wt_hi/lo[n][k] bf16 ----
__global__ __launch_bounds__(256) void conv_weights(
    const float* __restrict__ W1, const float* __restrict__ W2,
    const float* __restrict__ W3, const float* __restrict__ fcW,
    short* __restrict__ wt)
{
    int tid = blockIdx.x * 256 + threadIdx.x;
    if (tid < 49152) {
        int L = tid >> 14, e = tid & 16383;
        const float* W = (L == 0) ? W1 : (L == 1) ? W2 : W3;
        float v = W[e];                  // e = k*128 + n
        int k = e >> 7, n = e & 127;
        short hi, lo; split_bf16(v, hi, lo);
        wt[L * 32768 + n * 128 + k] = hi;
        wt[L * 32768 + 16384 + n * 128 + k] = lo;
    } else if (tid < 57344) {
        int e = tid - 49152;
        float v = fcW[e];                // e = k*64 + n
        int k = e >> 6, n = e & 63;
        short hi, lo; split_bf16(v, hi, lo);
        wt[98304 + n * 128 + k] = hi;
        wt[106496 + n * 128 + k] = lo;
    }
}

// ---- GRU scan: 1 thread per graph, latency-minimized step ----
__global__ __launch_bounds__(64) void gru_scan(
    const float* __restrict__ grc, const float* __restrict__ gzc,
    const float* __restrict__ gnc,
    const float* __restrict__ Whh, const float* __restrict__ bhh,
    const float* __restrict__ init_hs, float* __restrict__ out)
{
    const int g = blockIdx.x * 64 + threadIdx.x;    // 0..1023
    const float L2E = 1.4426950408889634f;
    const float wrc = -L2E * Whh[0];
    const float wzc = -L2E * Whh[1];
    const float wnc2 = 2.f * L2E * Whh[2];
    const float bnc2 = 2.f * L2E * bhh[2];
    const float* pr = grc + (size_t)g * EPG;
    const float* pz = gzc + (size_t)g * EPG;
    const float* pn = gnc + (size_t)g * EPG;
    float* flat = out + NG + (size_t)g * EPG;

    float h = init_hs[0];
    float ssum = 0.f, lastval = 0.f, firstval = 0.f;
    int lastidx = -1;

    float cr[4], cz[4], cn[4];
#pragma unroll
    for (int s = 0; s < 4; ++s) { cr[s] = pr[s]; cz[s] = pz[s]; cn[s] = pn[s]; }

    for (int tt = 0; tt < EPG; tt += 4) {
        float nr[4], nz[4], nn[4];
        if (tt + 4 < EPG) {
#pragma unroll
            for (int s = 0; s < 4; ++s) {
                nr[s] = pr[tt + 4 + s]; nz[s] = pz[tt + 4 + s]; nn[s] = pn[tt + 4 + s];
            }
        } else {
#pragma unroll
            for (int s = 0; s < 4; ++s) { nr[s] = cr[s]; nz[s] = cz[s]; nn[s] = cn[s]; }
        }
        float4 hq;
#pragma unroll
        for (int s = 0; s < 4; ++s) {
            float ur = fmaf(h, wrc, cr[s]);
            float uz = fmaf(h, wzc, cz[s]);
            float hn = fmaf(h, wnc2, bnc2);
            float r = __builtin_amdgcn_rcpf(1.f + __builtin_amdgcn_exp2f(ur));
            float z = __builtin_amdgcn_rcpf(1.f + __builtin_amdgcn_exp2f(uz));
            float xn = fmaf(r, hn, cn[s]);
            float q = __builtin_amdgcn_rcpf(1.f + __builtin_amdgcn_exp2f(xn));
            float A = 1.f - z;
            float C = fmaf(z, h, A);
            float m2A = -2.f * A;
            h = fmaf(q, m2A, C);       // (1-2q)(1-z) + z*h
            ((float*)&hq)[s] = h;
        }
        *(float4*)&flat[tt] = hq;
        if (tt == 0) firstval = hq.x;
        ssum += ((hq.x + hq.y) + (hq.z + hq.w));
        if (hq.x != 0.f) { lastidx = tt;     lastval = hq.x; }
        if (hq.y != 0.f) { lastidx = tt + 1; lastval = hq.y; }
        if (hq.z != 0.f) { lastidx = tt + 2; lastval = hq.z; }
        if (hq.w != 0.f) { lastidx = tt + 3; lastval = hq.w; }
#pragma unroll
        for (int s = 0; s < 4; ++s) { cr[s] = nr[s]; cz[s] = nz[s]; cn[s] = nn[s]; }
    }
    out[g] = (ssum > 0.f && lastidx >= 0) ? lastval : firstval;
}

extern "C" void kernel_launch(void* const* d_in, const int* in_sizes, int n_in,
                              void* d_out, int out_size, void* d_ws, size_t ws_size,
                              hipStream_t stream) {
    const float* x    = (const float*)d_in[0];
    const float* emb  = (const float*)d_in[1];
    const float* W1   = (const float*)d_in[2];
    const float* b1   = (const float*)d_in[3];
    const float* W2   = (const float*)d_in[4];
    const float* b2   = (const float*)d_in[5];
    const float* W3   = (const float*)d_in[6];
    const float* b3   = (const float*)d_in[7];
    const float* fcW  = (const float*)d_in[8];
    const float* fcb  = (const float*)d_in[9];
    const float* Wih  = (const float*)d_in[10];
    const float* Whh  = (const float*)d_in[11];
    const float* bih  = (const float*)d_in[12];
    const float* bhh  = (const float*)d_in[13];
    const float* ihs  = (const float*)d_in[14];
    const int*   ei   = (const int*)d_in[15];
    float* out = (float*)d_out;

    float* grc = (float*)d_ws;
    float* gzc = (float*)((char*)d_ws + (2u << 20));
    float* gnc = (float*)((char*)d_ws + (4u << 20));
    short* wt  = (short*)((char*)d_ws + (6u << 20));

    conv_weights<<<dim3(224), dim3(256), 0, stream>>>(W1, W2, W3, fcW, wt);
    fused_graph<<<dim3(NG), dim3(256), 0, stream>>>(
        x, emb, b1, b2, b3, fcb, Wih, bih, bhh, ei, wt, grc, gzc, gnc);
    gru_scan<<<dim3(16), dim3(64), 0, stream>>>(grc, gzc, gnc, Whh, bhh, ihs, out);
}